// Round 4
// baseline (688.651 us; speedup 1.0000x reference)
//
#include <hip/hip_runtime.h>

#define N_NODES 100000
#define N_EDGES 3200000
#define N_GRAPHS 256

// ======================= GEMMs =======================
__global__ __launch_bounds__(256) void gemm1_kernel(const float* __restrict__ x,
                                                    const float* __restrict__ W1,
                                                    float* __restrict__ out) {
    __shared__ float xs[16 * 128];
    __shared__ float w1s[128 * 16];
    const int tid = threadIdx.x;
    const int nb = blockIdx.x * 16;
#pragma unroll
    for (int i = 0; i < 8; ++i) w1s[tid + i * 256] = W1[tid + i * 256];
    const float* xsrc = x + (size_t)nb * 128;
#pragma unroll
    for (int i = 0; i < 8; ++i) xs[tid + i * 256] = xsrc[tid + i * 256];
    __syncthreads();
    const int ln = tid >> 4, oc = tid & 15;
    float acc = 0.f;
#pragma unroll 8
    for (int k = 0; k < 128; ++k)
        acc = fmaf(xs[ln * 128 + k], w1s[k * 16 + oc], acc);
    out[(size_t)(nb + ln) * 16 + oc] = acc;
}

__global__ __launch_bounds__(256) void gemm16_kernel(const float* __restrict__ h,
                                                     const float* __restrict__ W,
                                                     float* __restrict__ out) {
    __shared__ float hs[256];
    __shared__ float wsm[256];
    const int tid = threadIdx.x;
    const int nb = blockIdx.x * 16;
    wsm[tid] = W[tid];
    hs[tid] = h[(size_t)nb * 16 + tid];
    __syncthreads();
    const int ln = tid >> 4, oc = tid & 15;
    float acc = 0.f;
#pragma unroll
    for (int k = 0; k < 16; ++k)
        acc = fmaf(hs[ln * 16 + k], wsm[k * 16 + oc], acc);
    out[(size_t)(nb + ln) * 16 + oc] = acc;
}

// ======================= CSR build =======================
// hist: cnt[row[e]]++ ; exact grid 12500*256 == N_EDGES
__global__ __launch_bounds__(256) void hist_kernel(const int* __restrict__ row,
                                                   int* __restrict__ cnt) {
    const int e = blockIdx.x * 256 + threadIdx.x;
    atomicAdd(&cnt[row[e]], 1);
}

#define SCAN_CHUNK 1024
#define NB1 98  // ceil(N_NODES / SCAN_CHUNK)

__global__ __launch_bounds__(256) void scanA_kernel(const int* __restrict__ cnt,
                                                    int* __restrict__ bsum) {
    __shared__ int part[256];
    const int b = blockIdx.x, t = threadIdx.x;
    const int base = b * SCAN_CHUNK + t * 4;
    int s = 0;
#pragma unroll
    for (int i = 0; i < 4; ++i) { int idx = base + i; s += (idx < N_NODES) ? cnt[idx] : 0; }
    part[t] = s; __syncthreads();
    for (int off = 128; off > 0; off >>= 1) {
        if (t < off) part[t] += part[t + off];
        __syncthreads();
    }
    if (t == 0) bsum[b] = part[0];
}

__global__ __launch_bounds__(128) void scanB_kernel(const int* __restrict__ bsum,
                                                    int* __restrict__ boff,
                                                    int* __restrict__ ptr) {
    __shared__ int a[128];
    const int t = threadIdx.x;
    const int v = (t < NB1) ? bsum[t] : 0;
    a[t] = v; __syncthreads();
    for (int off = 1; off < 128; off <<= 1) {
        int u = (t >= off) ? a[t - off] : 0;
        __syncthreads();
        a[t] += u;
        __syncthreads();
    }
    if (t < NB1) boff[t] = a[t] - v;   // exclusive
    if (t == 0) ptr[N_NODES] = N_EDGES;
}

__global__ __launch_bounds__(256) void scanC_kernel(const int* __restrict__ cnt,
                                                    const int* __restrict__ boff,
                                                    int* __restrict__ ptr,
                                                    int* __restrict__ cur) {
    __shared__ int a[256];
    const int b = blockIdx.x, t = threadIdx.x;
    const int base = b * SCAN_CHUNK + t * 4;
    const int c0 = (base + 0 < N_NODES) ? cnt[base + 0] : 0;
    const int c1 = (base + 1 < N_NODES) ? cnt[base + 1] : 0;
    const int c2 = (base + 2 < N_NODES) ? cnt[base + 2] : 0;
    const int c3 = (base + 3 < N_NODES) ? cnt[base + 3] : 0;
    const int s = c0 + c1 + c2 + c3;
    a[t] = s; __syncthreads();
    for (int off = 1; off < 256; off <<= 1) {
        int u = (t >= off) ? a[t - off] : 0;
        __syncthreads();
        a[t] += u;
        __syncthreads();
    }
    int ex = a[t] - s + boff[b];
    const int p0 = ex, p1 = ex + c0, p2 = p1 + c1, p3 = p2 + c2;
    if (base + 0 < N_NODES) { ptr[base + 0] = p0; cur[base + 0] = p0; }
    if (base + 1 < N_NODES) { ptr[base + 1] = p1; cur[base + 1] = p1; }
    if (base + 2 < N_NODES) { ptr[base + 2] = p2; cur[base + 2] = p2; }
    if (base + 3 < N_NODES) { ptr[base + 3] = p3; cur[base + 3] = p3; }
}

// fill: ent[pos] = (col, w) bucketed by destination row
__global__ __launch_bounds__(256) void fill_kernel(const int* __restrict__ row,
                                                   const int* __restrict__ col,
                                                   const float* __restrict__ ew,
                                                   int* __restrict__ cur,
                                                   float2* __restrict__ ent) {
    const int e = blockIdx.x * 256 + threadIdx.x;
    const int r = row[e];
    const int pos = atomicAdd(&cur[r], 1);
    float2 v;
    v.x = __int_as_float(col[e]);
    v.y = ew[e];
    ent[pos] = v;
}

// ======================= Pull (per conv layer) =======================
// One wave per node: 4 edge slots x 16 channels. No atomics.
// Fused epilogue: out = elu(sum + bias)
__global__ __launch_bounds__(256) void pull_kernel(const float* __restrict__ h,
                                                   const float2* __restrict__ ent,
                                                   const int* __restrict__ ptr,
                                                   const float* __restrict__ bias,
                                                   float* __restrict__ out) {
    const int wid = (blockIdx.x * 256 + threadIdx.x) >> 6;  // node
    if (wid >= N_NODES) return;
    const int lane = threadIdx.x & 63;
    const int ch = lane & 15, slot = lane >> 4;
    const int beg = ptr[wid], end = ptr[wid + 1];
    float acc = 0.f;
    int e = beg + slot;
    for (; e + 4 < end; e += 8) {
        const float2 a0 = ent[e];
        const float2 a1 = ent[e + 4];
        acc += h[(size_t)__float_as_int(a0.x) * 16 + ch] * a0.y;
        acc += h[(size_t)__float_as_int(a1.x) * 16 + ch] * a1.y;
    }
    if (e < end) {
        const float2 a0 = ent[e];
        acc += h[(size_t)__float_as_int(a0.x) * 16 + ch] * a0.y;
    }
    acc += __shfl_xor(acc, 16);
    acc += __shfl_xor(acc, 32);
    if (lane < 16) {
        const float v = acc + bias[ch];
        out[(size_t)wid * 16 + lane] = v > 0.f ? v : expm1f(v);
    }
}

// ======================= Fallback path kernels (round-3 proven) =======================
__global__ __launch_bounds__(256) void scatter_kernel(const float* __restrict__ h,
                                                      const float* __restrict__ w,
                                                      const int* __restrict__ row,
                                                      const int* __restrict__ col,
                                                      float* __restrict__ agg) {
    const long long t = (long long)blockIdx.x * 256 + threadIdx.x;
    const int e = (int)(t >> 4);
    const int ch = (int)(t & 15);
    const int r = row[e], c = col[e];
    const float wt = w[e];
    const float v = h[(size_t)c * 16 + ch] * wt;
    atomicAdd(agg + (size_t)r * 16 + ch, v);
}

__global__ __launch_bounds__(256) void elubias_kernel(float* __restrict__ a,
                                                      const float* __restrict__ b) {
    __shared__ float bs[16];
    if (threadIdx.x < 16) bs[threadIdx.x] = b[threadIdx.x];
    __syncthreads();
    const int total = N_NODES * 16;
    for (int i = blockIdx.x * 256 + threadIdx.x; i < total; i += gridDim.x * 256) {
        float v = a[i] + bs[i & 15];
        a[i] = v > 0.f ? v : expm1f(v);
    }
}

// ======================= Pool + head =======================
#define POOL_NODES 1024
__global__ __launch_bounds__(256) void pool_kernel(const float* __restrict__ h,
                                                   const int* __restrict__ seg,
                                                   float* __restrict__ pooled) {
    __shared__ float lp[N_GRAPHS * 16];
    const int tid = threadIdx.x;
    for (int i = tid; i < N_GRAPHS * 16; i += 256) lp[i] = 0.f;
    __syncthreads();
    const int base = blockIdx.x * POOL_NODES;
    const int lim = min(base + POOL_NODES, N_NODES);
    for (int idx = base * 16 + tid; idx < lim * 16; idx += 256) {
        const int node = idx >> 4;
        const int ch = idx & 15;
        atomicAdd(&lp[seg[node] * 16 + ch], h[idx]);
    }
    __syncthreads();
    const int s0 = seg[base];
    const int s1 = seg[lim - 1];
    const int cnt = (s1 - s0 + 1) * 16;
    for (int j = tid; j < cnt; j += 256) {
        atomicAdd(&pooled[s0 * 16 + j], lp[s0 * 16 + j]);
    }
}

__global__ __launch_bounds__(256) void head_kernel(const float* __restrict__ pooled,
                                                   const float* __restrict__ Wd2,
                                                   const float* __restrict__ bd2,
                                                   const float* __restrict__ Wd3,
                                                   const float* __restrict__ bd3,
                                                   float* __restrict__ out) {
    __shared__ float w2[256], w3[32], b2s[16], b3s[2];
    const int tid = threadIdx.x;
    w2[tid] = Wd2[tid];
    if (tid < 32) w3[tid] = Wd3[tid];
    if (tid < 16) b2s[tid] = bd2[tid];
    if (tid < 2) b3s[tid] = bd3[tid];
    __syncthreads();
    const int g = tid;
    float p[16];
#pragma unroll
    for (int k = 0; k < 16; ++k) p[k] = pooled[g * 16 + k];
    float t[16];
#pragma unroll
    for (int j = 0; j < 16; ++j) {
        float acc = b2s[j];
#pragma unroll
        for (int k = 0; k < 16; ++k) acc = fmaf(p[k], w2[k * 16 + j], acc);
        t[j] = acc > 0.f ? acc : 0.f;
    }
#pragma unroll
    for (int m = 0; m < 2; ++m) {
        float acc = b3s[m];
#pragma unroll
        for (int j = 0; j < 16; ++j) acc = fmaf(t[j], w3[j * 2 + m], acc);
        out[g * 2 + m] = 1.f / (1.f + expf(-acc));
    }
}

extern "C" void kernel_launch(void* const* d_in, const int* in_sizes, int n_in,
                              void* d_out, int out_size, void* d_ws, size_t ws_size,
                              hipStream_t stream) {
    const float* x   = (const float*)d_in[0];
    const float* ew  = (const float*)d_in[1];
    const float* W1  = (const float*)d_in[2];
    const float* b1  = (const float*)d_in[3];
    const float* W2  = (const float*)d_in[4];
    const float* b2  = (const float*)d_in[5];
    const float* Wd2 = (const float*)d_in[6];
    const float* bd2 = (const float*)d_in[7];
    const float* Wd3 = (const float*)d_in[8];
    const float* bd3 = (const float*)d_in[9];
    const int* row   = (const int*)d_in[10];
    const int* col   = (const int*)d_in[11];
    const int* seg   = (const int*)d_in[12];
    float* out = (float*)d_out;

    // ---- workspace layout (CSR path) ----
    // ent[E]*8 | A 6.4MB | B 6.4MB | pooled 16KB | ptr (N+1)*4 | cnt N*4 | cur N*4 | bsum | boff
    char* wsc = (char*)d_ws;
    const size_t ENT_B = (size_t)N_EDGES * 8;                    // 25,600,000
    float2* ent   = (float2*)wsc;
    float*  A     = (float*)(wsc + ENT_B);                       // 6,400,000
    float*  B     = (float*)(wsc + ENT_B + 6400000);             // 6,400,000
    float*  pooled= (float*)(wsc + ENT_B + 12800000);            // 16,384
    int*    ptr   = (int*)  (wsc + ENT_B + 12816384);            // 400,004
    int*    cnt   = (int*)  (wsc + ENT_B + 13216388);            // 400,000
    int*    cur   = (int*)  (wsc + ENT_B + 13616388);            // 400,000
    int*    bsum  = (int*)  (wsc + ENT_B + 14016388);            // 392
    int*    boff  = (int*)  (wsc + ENT_B + 14016780);            // 392
    const size_t REQ = ENT_B + 14017172;

    const int EB = N_EDGES / 256;  // 12500 exact

    if (ws_size >= REQ) {
        // ---------- CSR build ----------
        hipMemsetAsync(cnt, 0, (size_t)N_NODES * 4, stream);
        hist_kernel<<<EB, 256, 0, stream>>>(row, cnt);
        scanA_kernel<<<NB1, 256, 0, stream>>>(cnt, bsum);
        scanB_kernel<<<1, 128, 0, stream>>>(bsum, boff, ptr);
        scanC_kernel<<<NB1, 256, 0, stream>>>(cnt, boff, ptr, cur);
        fill_kernel<<<EB, 256, 0, stream>>>(row, col, ew, cur, ent);

        // ---------- Layer 1 ----------
        gemm1_kernel<<<N_NODES / 16, 256, 0, stream>>>(x, W1, A);
        pull_kernel<<<(N_NODES * 64) / 256, 256, 0, stream>>>(A, ent, ptr, b1, B);

        // ---------- Layer 2 ----------
        gemm16_kernel<<<N_NODES / 16, 256, 0, stream>>>(B, W2, A);
        pull_kernel<<<(N_NODES * 64) / 256, 256, 0, stream>>>(A, ent, ptr, b2, B);

        // ---------- Pool + head ----------
        hipMemsetAsync(pooled, 0, N_GRAPHS * 16 * sizeof(float), stream);
        pool_kernel<<<(N_NODES + POOL_NODES - 1) / POOL_NODES, 256, 0, stream>>>(B, seg, pooled);
        head_kernel<<<1, 256, 0, stream>>>(pooled, Wd2, bd2, Wd3, bd3, out);
    } else {
        // ---------- fallback: round-3 proven scatter path ----------
        float* fA = (float*)d_ws;
        float* fB = fA + (size_t)N_NODES * 16;
        float* fpooled = fB + (size_t)N_NODES * 16;
        const size_t h_bytes = (size_t)N_NODES * 16 * sizeof(float);
        const int scatter_blocks = (int)(((long long)N_EDGES * 16) / 256);

        gemm1_kernel<<<N_NODES / 16, 256, 0, stream>>>(x, W1, fA);
        hipMemsetAsync(fB, 0, h_bytes, stream);
        scatter_kernel<<<scatter_blocks, 256, 0, stream>>>(fA, ew, row, col, fB);
        elubias_kernel<<<2048, 256, 0, stream>>>(fB, b1);

        gemm16_kernel<<<N_NODES / 16, 256, 0, stream>>>(fB, W2, fA);
        hipMemsetAsync(fB, 0, h_bytes, stream);
        scatter_kernel<<<scatter_blocks, 256, 0, stream>>>(fA, ew, row, col, fB);
        elubias_kernel<<<2048, 256, 0, stream>>>(fB, b2);

        hipMemsetAsync(fpooled, 0, N_GRAPHS * 16 * sizeof(float), stream);
        pool_kernel<<<(N_NODES + POOL_NODES - 1) / POOL_NODES, 256, 0, stream>>>(fB, seg, fpooled);
        head_kernel<<<1, 256, 0, stream>>>(fpooled, Wd2, bd2, Wd3, bd3, out);
    }
}